// Round 2
// baseline (1105.714 us; speedup 1.0000x reference)
//
#include <hip/hip_runtime.h>
#include <stdint.h>

typedef __bf16 bf16;
typedef __bf16 bf16x8 __attribute__((ext_vector_type(8)));
typedef float  f32x4  __attribute__((ext_vector_type(4)));

#define MFMA16(a, b, c) __builtin_amdgcn_mfma_f32_16x16x32_bf16((a), (b), (c), 0, 0, 0)

static constexpr int    Bn = 4, Tn = 2048, Cn = 2048, HD = 128;
static constexpr size_t TEN = (size_t)Bn * Tn * Cn;   // 16,777,216 elems

// ---------------------------------------------------------------------------
// Stage a 128x32 tile into bf16 LDS (row-major, stride 32).
// f32 source: 256 threads x 16 elems (4x float4), convert to bf16.
// ---------------------------------------------------------------------------
__device__ __forceinline__ void stage_f32tile(const float* __restrict__ src, int ldk,
                                              bf16* sdst, int tid) {
  const int r = tid >> 1, c = (tid & 1) * 16;
  const float* g = src + (size_t)r * ldk + c;
  float4 a = *(const float4*)(g);
  float4 b = *(const float4*)(g + 4);
  float4 d = *(const float4*)(g + 8);
  float4 e = *(const float4*)(g + 12);
  bf16x8 lo = {(bf16)a.x, (bf16)a.y, (bf16)a.z, (bf16)a.w,
               (bf16)b.x, (bf16)b.y, (bf16)b.z, (bf16)b.w};
  bf16x8 hi = {(bf16)d.x, (bf16)d.y, (bf16)d.z, (bf16)d.w,
               (bf16)e.x, (bf16)e.y, (bf16)e.z, (bf16)e.w};
  *(bf16x8*)&sdst[r * 32 + c]     = lo;
  *(bf16x8*)&sdst[r * 32 + c + 8] = hi;
}

__device__ __forceinline__ void stage_bf16tile(const bf16* __restrict__ src, int ldk,
                                               bf16* sdst, int tid) {
  const int r = tid >> 1, c = (tid & 1) * 16;
  const bf16* g = src + (size_t)r * ldk + c;
  *(uint4*)&sdst[r * 32 + c]     = *(const uint4*)(g);
  *(uint4*)&sdst[r * 32 + c + 8] = *(const uint4*)(g + 8);
}

// ---------------------------------------------------------------------------
// GEMM: C[M,N] = A[M,K] · Bt[N,K]^T, 128x128 tile, BK=32, 256 threads.
// A is f32 or bf16 (template), Bt is f32, C is f32 or bf16 (template).
// ---------------------------------------------------------------------------
template <bool A_F32, bool OUT_F32>
__device__ __forceinline__ void gemm_body(const void* __restrict__ Av,
                                          const float* __restrict__ Bt,
                                          void* __restrict__ Cv,
                                          int m0, int n0, int N, int K) {
  __shared__ bf16 sA[128 * 32];
  __shared__ bf16 sB[128 * 32];
  const int tid  = threadIdx.x;
  const int lane = tid & 63, wid = tid >> 6;
  const int quad = lane >> 4, l16 = lane & 15;
  const int wm = (wid & 1) * 64, wn = (wid >> 1) * 64;

  f32x4 acc[4][4] = {};

  for (int k0 = 0; k0 < K; k0 += 32) {
    if (A_F32)
      stage_f32tile((const float*)Av + (size_t)m0 * K + k0, K, sA, tid);
    else
      stage_bf16tile((const bf16*)Av + (size_t)m0 * K + k0, K, sA, tid);
    stage_f32tile(Bt + (size_t)n0 * K + k0, K, sB, tid);
    __syncthreads();

    bf16x8 af[4], bfr[4];
#pragma unroll
    for (int i = 0; i < 4; i++) {
      af[i]  = *(const bf16x8*)&sA[(wm + i * 16 + l16) * 32 + quad * 8];
      bfr[i] = *(const bf16x8*)&sB[(wn + i * 16 + l16) * 32 + quad * 8];
    }
#pragma unroll
    for (int im = 0; im < 4; im++)
#pragma unroll
      for (int in = 0; in < 4; in++)
        acc[im][in] = MFMA16(af[im], bfr[in], acc[im][in]);
    __syncthreads();
  }

#pragma unroll
  for (int im = 0; im < 4; im++)
#pragma unroll
    for (int in = 0; in < 4; in++)
#pragma unroll
      for (int r = 0; r < 4; r++) {
        int row = m0 + wm + im * 16 + quad * 4 + r;   // C/D: row = quad*4+reg
        int col = n0 + wn + in * 16 + l16;            //      col = lane&15
        if (OUT_F32)
          ((float*)Cv)[(size_t)row * N + col] = acc[im][in][r];
        else
          ((bf16*)Cv)[(size_t)row * N + col] = (bf16)acc[im][in][r];
      }
}

// QKV fused: grid.x = 48 (3 outputs x 16 n-tiles), grid.y = 64 (m-tiles)
__global__ __launch_bounds__(256) void qkv_gemm(const float* __restrict__ X,
                                                const float* __restrict__ Wq,
                                                const float* __restrict__ Wk,
                                                const float* __restrict__ Wv,
                                                bf16* __restrict__ qkv) {
  const int sel = blockIdx.x >> 4;
  const float* Bt = (sel == 0) ? Wq : (sel == 1) ? Wk : Wv;
  bf16* out = qkv + (size_t)sel * TEN;
  gemm_body<true, false>(X, Bt, out, blockIdx.y * 128, (blockIdx.x & 15) * 128, Cn, Cn);
}

// Output projection: A = y (bf16), Bt = Wp (f32), out f32
__global__ __launch_bounds__(256) void out_gemm(const bf16* __restrict__ Y,
                                                const float* __restrict__ Wp,
                                                float* __restrict__ O) {
  gemm_body<false, true>(Y, Wp, O, blockIdx.y * 128, blockIdx.x * 128, Cn, Cn);
}

// ---------------------------------------------------------------------------
// RoPE in place on bf16 q and k (grid.y selects tensor).
// ---------------------------------------------------------------------------
__global__ __launch_bounds__(256) void rope_qk(bf16* __restrict__ qk) {
  bf16* p = qk + (size_t)blockIdx.y * TEN;
  const int idx = blockIdx.x * 256 + threadIdx.x;   // pair index
  const int row = idx >> 10;                        // B*T row
  const int pp  = idx & 1023;
  const int i   = pp & 63;
  const int col0 = (pp >> 6) * 128 + 2 * i;
  const int t = row & (Tn - 1);
  const float ang = (float)t * __expf(-(float)i * 0.14391156831212787f); // ln(1e4)/64
  float s, c;
  sincosf(ang, &s, &c);
  uint32_t* addr = (uint32_t*)(p + (size_t)row * Cn + col0);
  const uint32_t u = *addr;
  const float xe = __uint_as_float((u & 0xffffu) << 16);
  const float xo = __uint_as_float(u & 0xffff0000u);
  const bf16 re = (bf16)(xe * c - xo * s);
  const bf16 ro = (bf16)(xo * c + xe * s);
  *addr = ((uint32_t)__builtin_bit_cast(uint16_t, ro) << 16) |
          (uint32_t)__builtin_bit_cast(uint16_t, re);
}

// ---------------------------------------------------------------------------
// V transpose: v (B*T, C) -> vt (B, C, T), 64x64 tiles, LDS stride 65.
// ---------------------------------------------------------------------------
__global__ __launch_bounds__(256) void transpose_v(const bf16* __restrict__ v,
                                                   bf16* __restrict__ vt) {
  __shared__ bf16 tile[64 * 65];
  const int tid = threadIdx.x;
  const int t0 = blockIdx.x * 64, c0 = blockIdx.y * 64, b = blockIdx.z;
  const bf16* src = v + ((size_t)(b * Tn + t0)) * Cn + c0;
  bf16* dst = vt + ((size_t)(b * Cn + c0)) * Tn + t0;
#pragma unroll
  for (int i = 0; i < 16; i++) {
    int lin = i * 256 + tid;
    int r = lin >> 6, c = lin & 63;
    tile[r * 65 + c] = src[(size_t)r * Cn + c];
  }
  __syncthreads();
#pragma unroll
  for (int i = 0; i < 16; i++) {
    int lin = i * 256 + tid;
    int cc = lin >> 6, t = lin & 63;
    dst[(size_t)cc * Tn + t] = tile[t * 65 + cc];
  }
}

// ---------------------------------------------------------------------------
// Causal flash attention. Block = (qt, bh): 64 q-rows of one (b,h).
// ---------------------------------------------------------------------------
__global__ __launch_bounds__(256) void attn(const bf16* __restrict__ q,
                                            const bf16* __restrict__ k,
                                            const bf16* __restrict__ vt,
                                            bf16* __restrict__ y) {
  __shared__ bf16 sK[64 * 136];    // K tile (64 keys x 128 d), stride 136
  __shared__ bf16 sVt[128 * 72];   // V^T tile (128 d x 64 keys), stride 72
  __shared__ bf16 sP[64 * 72];     // P tile (64 q x 64 keys), stride 72

  const int tid = threadIdx.x;
  const int qt = blockIdx.x, bh = blockIdx.y;
  const int b = bh >> 4, h = bh & 15;
  const int q0 = qt * 64;
  const int lane = tid & 63, w = tid >> 6;
  const int quad = lane >> 4, l16 = lane & 15;

  const bf16* qbase  = q + ((size_t)(b * Tn + q0)) * Cn + h * HD;
  const bf16* kbase  = k + ((size_t)(b * Tn)) * Cn + h * HD;
  const bf16* vtbase = vt + ((size_t)(b * Cn + h * HD)) * Tn;

#pragma unroll
  for (int i = 0; i < 4; i++) {
    int lin = i * 256 + tid;
    int row = lin >> 4, c8 = (lin & 15) * 8;
    *(uint4*)&sK[row * 136 + c8] = *(const uint4*)(qbase + (size_t)row * Cn + c8);
  }
  __syncthreads();
  bf16x8 qf[4];
#pragma unroll
  for (int s = 0; s < 4; s++)
    qf[s] = *(const bf16x8*)&sK[(w * 16 + l16) * 136 + s * 32 + quad * 8];

  f32x4 O[8] = {};
  float mrow[4], lrow[4];
#pragma unroll
  for (int r = 0; r < 4; r++) { mrow[r] = -1e30f; lrow[r] = 0.f; }
  const float scale = 0.08838834764831845f;   // 1/sqrt(128)

  for (int kt = 0; kt <= qt; kt++) {
    __syncthreads();   // previous iteration's readers (and qf reads) done
#pragma unroll
    for (int i = 0; i < 4; i++) {            // stage K tile
      int lin = i * 256 + tid;
      int row = lin >> 4, c8 = (lin & 15) * 8;
      *(uint4*)&sK[row * 136 + c8] =
          *(const uint4*)(kbase + (size_t)(kt * 64 + row) * Cn + c8);
    }
#pragma unroll
    for (int i = 0; i < 4; i++) {            // stage V^T tile
      int lin = i * 256 + tid;
      int drow = lin >> 3, k8 = (lin & 7) * 8;
      *(uint4*)&sVt[drow * 72 + k8] =
          *(const uint4*)(vtbase + (size_t)drow * Tn + kt * 64 + k8);
    }
    __syncthreads();

    f32x4 sv[4] = {};
#pragma unroll
    for (int s = 0; s < 4; s++) {
      bf16x8 qfs = qf[s];
#pragma unroll
      for (int jn = 0; jn < 4; jn++) {
        bf16x8 kf = *(const bf16x8*)&sK[(jn * 16 + l16) * 136 + s * 32 + quad * 8];
        sv[jn] = MFMA16(qfs, kf, sv[jn]);
      }
    }

    const bool diag = (kt == qt);
    float p[4][4];
#pragma unroll
    for (int r = 0; r < 4; r++) {
      float mx = -1e30f;
#pragma unroll
      for (int jn = 0; jn < 4; jn++) {
        float x = sv[jn][r] * scale;
        if (diag) {
          int key = jn * 16 + l16;
          int qr  = w * 16 + quad * 4 + r;
          if (key > qr) x = -1e30f;
        }
        p[jn][r] = x;
        mx = fmaxf(mx, x);
      }
      mx = fmaxf(mx, __shfl_xor(mx, 1));
      mx = fmaxf(mx, __shfl_xor(mx, 2));
      mx = fmaxf(mx, __shfl_xor(mx, 4));
      mx = fmaxf(mx, __shfl_xor(mx, 8));
      const float mn = fmaxf(mrow[r], mx);
      const float alpha = __expf(mrow[r] - mn);
      mrow[r] = mn;
      float rs = 0.f;
#pragma unroll
      for (int jn = 0; jn < 4; jn++) {
        float e = __expf(p[jn][r] - mn);
        p[jn][r] = e;
        rs += e;
      }
      rs += __shfl_xor(rs, 1);
      rs += __shfl_xor(rs, 2);
      rs += __shfl_xor(rs, 4);
      rs += __shfl_xor(rs, 8);
      lrow[r] = lrow[r] * alpha + rs;
#pragma unroll
      for (int n = 0; n < 8; n++) O[n][r] *= alpha;
    }

    // P (C-layout regs) -> LDS bf16 -> A-layout frags; rows are wave-private
#pragma unroll
    for (int r = 0; r < 4; r++)
#pragma unroll
      for (int jn = 0; jn < 4; jn++)
        sP[(w * 16 + quad * 4 + r) * 72 + jn * 16 + l16] = (bf16)p[jn][r];

#pragma unroll
    for (int s2 = 0; s2 < 2; s2++) {
      bf16x8 pf = *(const bf16x8*)&sP[(w * 16 + l16) * 72 + s2 * 32 + quad * 8];
#pragma unroll
      for (int n = 0; n < 8; n++) {
        bf16x8 vf = *(const bf16x8*)&sVt[(n * 16 + l16) * 72 + s2 * 32 + quad * 8];
        O[n] = MFMA16(pf, vf, O[n]);
      }
    }
  }

  bf16* ybase = y + ((size_t)(b * Tn + q0 + w * 16)) * Cn + h * HD;
#pragma unroll
  for (int r = 0; r < 4; r++) {
    const float inv = 1.f / lrow[r];
#pragma unroll
    for (int n = 0; n < 8; n++)
      ybase[(size_t)(quad * 4 + r) * Cn + n * 16 + l16] = (bf16)(O[n][r] * inv);
  }
}

// ---------------------------------------------------------------------------
extern "C" void kernel_launch(void* const* d_in, const int* in_sizes, int n_in,
                              void* d_out, int out_size, void* d_ws, size_t ws_size,
                              hipStream_t stream) {
  (void)in_sizes; (void)n_in; (void)out_size; (void)ws_size;
  const float* x  = (const float*)d_in[0];
  const float* Wq = (const float*)d_in[1];
  const float* Wk = (const float*)d_in[2];
  const float* Wv = (const float*)d_in[3];
  const float* Wp = (const float*)d_in[4];
  float* out = (float*)d_out;
  bf16*  ws  = (bf16*)d_ws;

  bf16* q  = ws;                 // (B*T, C) bf16
  bf16* kk = ws + TEN;           // (B*T, C) bf16
  bf16* v  = ws + 2 * TEN;       // (B*T, C) bf16
  bf16* vt = ws + 3 * TEN;       // (B, C, T) bf16
  bf16* y  = ws + 4 * TEN;       // (B*T, C) bf16

  qkv_gemm   <<<dim3(48, 64), 256, 0, stream>>>(x, Wq, Wk, Wv, ws);
  rope_qk    <<<dim3(32768, 2), 256, 0, stream>>>(ws);
  transpose_v<<<dim3(32, 32, 4), 256, 0, stream>>>(v, vt);
  attn       <<<dim3(32, 64), 256, 0, stream>>>(q, kk, vt, y);
  out_gemm   <<<dim3(16, 64), 256, 0, stream>>>(y, Wp, out);
}

// Round 3
// 875.534 us; speedup vs baseline: 1.2629x; 1.2629x over previous
//
#include <hip/hip_runtime.h>
#include <stdint.h>

typedef __bf16 bf16;
typedef __bf16 bf16x8 __attribute__((ext_vector_type(8)));
typedef float  f32x4  __attribute__((ext_vector_type(4)));

#define MFMA16(a, b, c) __builtin_amdgcn_mfma_f32_16x16x32_bf16((a), (b), (c), 0, 0, 0)

static constexpr int    Bn = 4, Tn = 2048, Cn = 2048, HD = 128;
static constexpr size_t TEN = (size_t)Bn * Tn * Cn;   // 16,777,216 elems

__device__ __forceinline__ void gld16(const void* g, void* l) {
  __builtin_amdgcn_global_load_lds(
      (const __attribute__((address_space(1))) void*)g,
      (__attribute__((address_space(3))) void*)l, 16, 0, 0);
}

// ---------------------------------------------------------------------------
// f32 -> bf16 conversion, 8 elems/thread (2x float4 in, 1x bf16x8 out)
// ---------------------------------------------------------------------------
__global__ __launch_bounds__(256) void to_bf16(const float* __restrict__ src,
                                               bf16* __restrict__ dst) {
  const size_t i = ((size_t)blockIdx.x * 256 + threadIdx.x) * 8;
  float4 a = *(const float4*)(src + i);
  float4 b = *(const float4*)(src + i + 4);
  bf16x8 o = {(bf16)a.x, (bf16)a.y, (bf16)a.z, (bf16)a.w,
              (bf16)b.x, (bf16)b.y, (bf16)b.z, (bf16)b.w};
  *(bf16x8*)(dst + i) = o;
}

// ---------------------------------------------------------------------------
// GEMM: C[M,N] = A[M,K] · Bt[N,K]^T (bf16 in, fp32 acc), 128x128 tile, BK=32,
// 256 threads, global_load_lds width-16 staging (m97 structure).
// ---------------------------------------------------------------------------
template <bool OUT_F32>
__device__ __forceinline__ void gemm_body(const bf16* __restrict__ A,
                                          const bf16* __restrict__ Bt,
                                          void* __restrict__ Cv,
                                          int m0, int n0, int N, int K) {
  __shared__ bf16 sA[128 * 32];
  __shared__ bf16 sB[128 * 32];
  const int tid  = threadIdx.x;
  const int lane = tid & 63, wid = tid >> 6;
  const int quad = lane >> 4, l16 = lane & 15;
  const int wm = (wid & 1) * 64, wn = (wid >> 1) * 64;

  f32x4 acc[4][4] = {};

  const int e0 = tid * 8;            // element index of this thread's 16B chunk
  const int r0 = e0 >> 5, c0 = e0 & 31;
  const bf16* gA = A + (size_t)(m0 + r0) * K + c0;
  const bf16* gB = Bt + (size_t)(n0 + r0) * K + c0;

  for (int k0 = 0; k0 < K; k0 += 32) {
    gld16(gA,                  &sA[e0]);
    gld16(gA + (size_t)64 * K, &sA[e0 + 2048]);
    gld16(gB,                  &sB[e0]);
    gld16(gB + (size_t)64 * K, &sB[e0 + 2048]);
    gA += 32; gB += 32;
    __syncthreads();                 // drains vmcnt: LDS tiles valid

    bf16x8 af[4], bfr[4];
#pragma unroll
    for (int i = 0; i < 4; i++) {
      af[i]  = *(const bf16x8*)&sA[(wm + i * 16 + l16) * 32 + quad * 8];
      bfr[i] = *(const bf16x8*)&sB[(wn + i * 16 + l16) * 32 + quad * 8];
    }
#pragma unroll
    for (int im = 0; im < 4; im++)
#pragma unroll
      for (int in = 0; in < 4; in++)
        acc[im][in] = MFMA16(af[im], bfr[in], acc[im][in]);
    __syncthreads();
  }

#pragma unroll
  for (int im = 0; im < 4; im++)
#pragma unroll
    for (int in = 0; in < 4; in++)
#pragma unroll
      for (int r = 0; r < 4; r++) {
        int row = m0 + wm + im * 16 + quad * 4 + r;   // C/D: row = quad*4+reg
        int col = n0 + wn + in * 16 + l16;            //      col = lane&15
        if (OUT_F32)
          ((float*)Cv)[(size_t)row * N + col] = acc[im][in][r];
        else
          ((bf16*)Cv)[(size_t)row * N + col] = (bf16)acc[im][in][r];
      }
}

// QKV fused: grid.x = 48 (3 outputs x 16 n-tiles), grid.y = 64 (m-tiles)
__global__ __launch_bounds__(256) void qkv_gemm(const bf16* __restrict__ X,
                                                const bf16* __restrict__ Wq,
                                                const bf16* __restrict__ Wk,
                                                const bf16* __restrict__ Wv,
                                                bf16* __restrict__ qkv) {
  const int sel = blockIdx.x >> 4;
  const bf16* Bt = (sel == 0) ? Wq : (sel == 1) ? Wk : Wv;
  bf16* out = qkv + (size_t)sel * TEN;
  gemm_body<false>(X, Bt, out, blockIdx.y * 128, (blockIdx.x & 15) * 128, Cn, Cn);
}

// Output projection: A = y (bf16), Bt = Wp (bf16), out f32
__global__ __launch_bounds__(256) void out_gemm(const bf16* __restrict__ Y,
                                                const bf16* __restrict__ Wp,
                                                float* __restrict__ O) {
  gemm_body<true>(Y, Wp, O, blockIdx.y * 128, blockIdx.x * 128, Cn, Cn);
}

// ---------------------------------------------------------------------------
// RoPE in place on bf16 q and k (grid.y selects tensor).
// ---------------------------------------------------------------------------
__global__ __launch_bounds__(256) void rope_qk(bf16* __restrict__ qk) {
  bf16* p = qk + (size_t)blockIdx.y * TEN;
  const int idx = blockIdx.x * 256 + threadIdx.x;   // pair index
  const int row = idx >> 10;                        // B*T row
  const int pp  = idx & 1023;
  const int i   = pp & 63;
  const int col0 = (pp >> 6) * 128 + 2 * i;
  const int t = row & (Tn - 1);
  const float ang = (float)t * __expf(-(float)i * 0.14391156831212787f); // ln(1e4)/64
  float s, c;
  sincosf(ang, &s, &c);
  uint32_t* addr = (uint32_t*)(p + (size_t)row * Cn + col0);
  const uint32_t u = *addr;
  const float xe = __uint_as_float((u & 0xffffu) << 16);
  const float xo = __uint_as_float(u & 0xffff0000u);
  const bf16 re = (bf16)(xe * c - xo * s);
  const bf16 ro = (bf16)(xo * c + xe * s);
  *addr = ((uint32_t)__builtin_bit_cast(uint16_t, ro) << 16) |
          (uint32_t)__builtin_bit_cast(uint16_t, re);
}

// ---------------------------------------------------------------------------
// V transpose: v (B*T, C) -> vt (B, C, T), 64x64 tiles, LDS stride 65.
// ---------------------------------------------------------------------------
__global__ __launch_bounds__(256) void transpose_v(const bf16* __restrict__ v,
                                                   bf16* __restrict__ vt) {
  __shared__ bf16 tile[64 * 65];
  const int tid = threadIdx.x;
  const int t0 = blockIdx.x * 64, c0 = blockIdx.y * 64, b = blockIdx.z;
  const bf16* src = v + ((size_t)(b * Tn + t0)) * Cn + c0;
  bf16* dst = vt + ((size_t)(b * Cn + c0)) * Tn + t0;
#pragma unroll
  for (int i = 0; i < 16; i++) {
    int lin = i * 256 + tid;
    int r = lin >> 6, c = lin & 63;
    tile[r * 65 + c] = src[(size_t)r * Cn + c];
  }
  __syncthreads();
#pragma unroll
  for (int i = 0; i < 16; i++) {
    int lin = i * 256 + tid;
    int cc = lin >> 6, t = lin & 63;
    dst[(size_t)cc * Tn + t] = tile[t * 65 + cc];
  }
}

// ---------------------------------------------------------------------------
// Causal flash attention. Block = (qt, bh): 64 q-rows of one (b,h).
// ---------------------------------------------------------------------------
__global__ __launch_bounds__(256) void attn(const bf16* __restrict__ q,
                                            const bf16* __restrict__ k,
                                            const bf16* __restrict__ vt,
                                            bf16* __restrict__ y) {
  __shared__ bf16 sK[64 * 136];    // K tile (64 keys x 128 d), stride 136
  __shared__ bf16 sVt[128 * 72];   // V^T tile (128 d x 64 keys), stride 72
  __shared__ bf16 sP[64 * 72];     // P tile (64 q x 64 keys), stride 72

  const int tid = threadIdx.x;
  const int qt = blockIdx.x, bh = blockIdx.y;
  const int b = bh >> 4, h = bh & 15;
  const int q0 = qt * 64;
  const int lane = tid & 63, w = tid >> 6;
  const int quad = lane >> 4, l16 = lane & 15;

  const bf16* qbase  = q + ((size_t)(b * Tn + q0)) * Cn + h * HD;
  const bf16* kbase  = k + ((size_t)(b * Tn)) * Cn + h * HD;
  const bf16* vtbase = vt + ((size_t)(b * Cn + h * HD)) * Tn;

#pragma unroll
  for (int i = 0; i < 4; i++) {
    int lin = i * 256 + tid;
    int row = lin >> 4, c8 = (lin & 15) * 8;
    *(uint4*)&sK[row * 136 + c8] = *(const uint4*)(qbase + (size_t)row * Cn + c8);
  }
  __syncthreads();
  bf16x8 qf[4];
#pragma unroll
  for (int s = 0; s < 4; s++)
    qf[s] = *(const bf16x8*)&sK[(w * 16 + l16) * 136 + s * 32 + quad * 8];

  f32x4 O[8] = {};
  float mrow[4], lrow[4];
#pragma unroll
  for (int r = 0; r < 4; r++) { mrow[r] = -1e30f; lrow[r] = 0.f; }
  const float scale = 0.08838834764831845f;   // 1/sqrt(128)

  for (int kt = 0; kt <= qt; kt++) {
    __syncthreads();   // previous iteration's readers (and qf reads) done
#pragma unroll
    for (int i = 0; i < 4; i++) {            // stage K tile
      int lin = i * 256 + tid;
      int row = lin >> 4, c8 = (lin & 15) * 8;
      *(uint4*)&sK[row * 136 + c8] =
          *(const uint4*)(kbase + (size_t)(kt * 64 + row) * Cn + c8);
    }
#pragma unroll
    for (int i = 0; i < 4; i++) {            // stage V^T tile
      int lin = i * 256 + tid;
      int drow = lin >> 3, k8 = (lin & 7) * 8;
      *(uint4*)&sVt[drow * 72 + k8] =
          *(const uint4*)(vtbase + (size_t)drow * Tn + kt * 64 + k8);
    }
    __syncthreads();

    f32x4 sv[4] = {};
#pragma unroll
    for (int s = 0; s < 4; s++) {
      bf16x8 qfs = qf[s];
#pragma unroll
      for (int jn = 0; jn < 4; jn++) {
        bf16x8 kf = *(const bf16x8*)&sK[(jn * 16 + l16) * 136 + s * 32 + quad * 8];
        sv[jn] = MFMA16(qfs, kf, sv[jn]);
      }
    }

    const bool diag = (kt == qt);
    float p[4][4];
#pragma unroll
    for (int r = 0; r < 4; r++) {
      float mx = -1e30f;
#pragma unroll
      for (int jn = 0; jn < 4; jn++) {
        float x = sv[jn][r] * scale;
        if (diag) {
          int key = jn * 16 + l16;
          int qr  = w * 16 + quad * 4 + r;
          if (key > qr) x = -1e30f;
        }
        p[jn][r] = x;
        mx = fmaxf(mx, x);
      }
      mx = fmaxf(mx, __shfl_xor(mx, 1));
      mx = fmaxf(mx, __shfl_xor(mx, 2));
      mx = fmaxf(mx, __shfl_xor(mx, 4));
      mx = fmaxf(mx, __shfl_xor(mx, 8));
      const float mn = fmaxf(mrow[r], mx);
      const float alpha = __expf(mrow[r] - mn);
      mrow[r] = mn;
      float rs = 0.f;
#pragma unroll
      for (int jn = 0; jn < 4; jn++) {
        float e = __expf(p[jn][r] - mn);
        p[jn][r] = e;
        rs += e;
      }
      rs += __shfl_xor(rs, 1);
      rs += __shfl_xor(rs, 2);
      rs += __shfl_xor(rs, 4);
      rs += __shfl_xor(rs, 8);
      lrow[r] = lrow[r] * alpha + rs;
#pragma unroll
      for (int n = 0; n < 8; n++) O[n][r] *= alpha;
    }

    // P (C-layout regs) -> LDS bf16 -> A-layout frags; rows are wave-private
#pragma unroll
    for (int r = 0; r < 4; r++)
#pragma unroll
      for (int jn = 0; jn < 4; jn++)
        sP[(w * 16 + quad * 4 + r) * 72 + jn * 16 + l16] = (bf16)p[jn][r];

#pragma unroll
    for (int s2 = 0; s2 < 2; s2++) {
      bf16x8 pf = *(const bf16x8*)&sP[(w * 16 + l16) * 72 + s2 * 32 + quad * 8];
#pragma unroll
      for (int n = 0; n < 8; n++) {
        bf16x8 vf = *(const bf16x8*)&sVt[(n * 16 + l16) * 72 + s2 * 32 + quad * 8];
        O[n] = MFMA16(pf, vf, O[n]);
      }
    }
  }

  bf16* ybase = y + ((size_t)(b * Tn + q0 + w * 16)) * Cn + h * HD;
#pragma unroll
  for (int r = 0; r < 4; r++) {
    const float inv = 1.f / lrow[r];
#pragma unroll
    for (int n = 0; n < 8; n++)
      ybase[(size_t)(quad * 4 + r) * Cn + n * 16 + l16] = (bf16)(O[n][r] * inv);
  }
}

// ---------------------------------------------------------------------------
// Workspace layout (bf16 elems), 5.25*TEN = 168 MB total:
//   q:0  k:TEN  v:2TEN
//   vt:3TEN            (aliases wq/wk/wv-bf16, dead after qkv_gemm)
//   xb/y:4TEN          (xb dead after qkv_gemm; y written by attn)
//   wpb:5TEN..5.25TEN  (live until out_gemm)
// ---------------------------------------------------------------------------
extern "C" void kernel_launch(void* const* d_in, const int* in_sizes, int n_in,
                              void* d_out, int out_size, void* d_ws, size_t ws_size,
                              hipStream_t stream) {
  (void)in_sizes; (void)n_in; (void)out_size; (void)ws_size;
  const float* x  = (const float*)d_in[0];
  const float* Wq = (const float*)d_in[1];
  const float* Wk = (const float*)d_in[2];
  const float* Wv = (const float*)d_in[3];
  const float* Wp = (const float*)d_in[4];
  float* out = (float*)d_out;
  bf16*  ws  = (bf16*)d_ws;

  bf16* q   = ws;                    // (B*T, C)
  bf16* kk  = ws + TEN;              // (B*T, C)
  bf16* v   = ws + 2 * TEN;          // (B*T, C)
  bf16* vt  = ws + 3 * TEN;          // (B, C, T)
  bf16* wqb = ws + 3 * TEN;          // alias vt
  bf16* wkb = ws + 3 * TEN + TEN / 4;
  bf16* wvb = ws + 3 * TEN + TEN / 2;
  bf16* xb  = ws + 4 * TEN;          // alias y
  bf16* y   = ws + 4 * TEN;
  bf16* wpb = ws + 5 * TEN;

  to_bf16    <<<dim3(8192), 256, 0, stream>>>(x, xb);
  to_bf16    <<<dim3(2048), 256, 0, stream>>>(Wq, wqb);
  to_bf16    <<<dim3(2048), 256, 0, stream>>>(Wk, wkb);
  to_bf16    <<<dim3(2048), 256, 0, stream>>>(Wv, wvb);
  to_bf16    <<<dim3(2048), 256, 0, stream>>>(Wp, wpb);
  qkv_gemm   <<<dim3(48, 64), 256, 0, stream>>>(xb, wqb, wkb, wvb, ws);
  rope_qk    <<<dim3(32768, 2), 256, 0, stream>>>(ws);
  transpose_v<<<dim3(32, 32, 4), 256, 0, stream>>>(v, vt);
  attn       <<<dim3(32, 64), 256, 0, stream>>>(q, kk, vt, y);
  out_gemm   <<<dim3(16, 64), 256, 0, stream>>>(y, wpb, out);
}

// Round 4
// 718.663 us; speedup vs baseline: 1.5386x; 1.2183x over previous
//
#include <hip/hip_runtime.h>
#include <stdint.h>

typedef __bf16 bf16;
typedef __bf16 bf16x8 __attribute__((ext_vector_type(8)));
typedef float  f32x4  __attribute__((ext_vector_type(4)));

#define MFMA16(a, b, c) __builtin_amdgcn_mfma_f32_16x16x32_bf16((a), (b), (c), 0, 0, 0)

static constexpr int    Bn = 4, Tn = 2048, Cn = 2048, HD = 128;
static constexpr size_t TEN = (size_t)Bn * Tn * Cn;   // 16,777,216 elems

__device__ __forceinline__ void gld16(const void* g, void* l) {
  __builtin_amdgcn_global_load_lds(
      (const __attribute__((address_space(1))) void*)g,
      (__attribute__((address_space(3))) void*)l, 16, 0, 0);
}

// ---------------------------------------------------------------------------
// f32 -> bf16 conversion, 8 elems/thread
// ---------------------------------------------------------------------------
__global__ __launch_bounds__(256) void to_bf16(const float* __restrict__ src,
                                               bf16* __restrict__ dst) {
  const size_t i = ((size_t)blockIdx.x * 256 + threadIdx.x) * 8;
  float4 a = *(const float4*)(src + i);
  float4 b = *(const float4*)(src + i + 4);
  bf16x8 o = {(bf16)a.x, (bf16)a.y, (bf16)a.z, (bf16)a.w,
              (bf16)b.x, (bf16)b.y, (bf16)b.z, (bf16)b.w};
  *(bf16x8*)(dst + i) = o;
}

// ---------------------------------------------------------------------------
// GEMM: C[M,N] = A[M,K] · Bt[N,K]^T (bf16 in, fp32 acc), 128x128 tile, BK=32,
// 256 threads, global_load_lds width-16 staging (m97 structure).
// ---------------------------------------------------------------------------
template <bool OUT_F32>
__device__ __forceinline__ void gemm_body(const bf16* __restrict__ A,
                                          const bf16* __restrict__ Bt,
                                          void* __restrict__ Cv,
                                          int m0, int n0, int N, int K) {
  __shared__ bf16 sA[128 * 32];
  __shared__ bf16 sB[128 * 32];
  const int tid  = threadIdx.x;
  const int lane = tid & 63, wid = tid >> 6;
  const int quad = lane >> 4, l16 = lane & 15;
  const int wm = (wid & 1) * 64, wn = (wid >> 1) * 64;

  f32x4 acc[4][4] = {};

  const int e0 = tid * 8;
  const int r0 = e0 >> 5, c0 = e0 & 31;
  const bf16* gA = A + (size_t)(m0 + r0) * K + c0;
  const bf16* gB = Bt + (size_t)(n0 + r0) * K + c0;

  for (int k0 = 0; k0 < K; k0 += 32) {
    gld16(gA,                  &sA[e0]);
    gld16(gA + (size_t)64 * K, &sA[e0 + 2048]);
    gld16(gB,                  &sB[e0]);
    gld16(gB + (size_t)64 * K, &sB[e0 + 2048]);
    gA += 32; gB += 32;
    __syncthreads();

    bf16x8 af[4], bfr[4];
#pragma unroll
    for (int i = 0; i < 4; i++) {
      af[i]  = *(const bf16x8*)&sA[(wm + i * 16 + l16) * 32 + quad * 8];
      bfr[i] = *(const bf16x8*)&sB[(wn + i * 16 + l16) * 32 + quad * 8];
    }
#pragma unroll
    for (int im = 0; im < 4; im++)
#pragma unroll
      for (int in = 0; in < 4; in++)
        acc[im][in] = MFMA16(af[im], bfr[in], acc[im][in]);
    __syncthreads();
  }

#pragma unroll
  for (int im = 0; im < 4; im++)
#pragma unroll
    for (int in = 0; in < 4; in++)
#pragma unroll
      for (int r = 0; r < 4; r++) {
        int row = m0 + wm + im * 16 + quad * 4 + r;
        int col = n0 + wn + in * 16 + l16;
        if (OUT_F32)
          ((float*)Cv)[(size_t)row * N + col] = acc[im][in][r];
        else
          ((bf16*)Cv)[(size_t)row * N + col] = (bf16)acc[im][in][r];
      }
}

__global__ __launch_bounds__(256) void qkv_gemm(const bf16* __restrict__ X,
                                                const bf16* __restrict__ Wq,
                                                const bf16* __restrict__ Wk,
                                                const bf16* __restrict__ Wv,
                                                bf16* __restrict__ qkv) {
  const int sel = blockIdx.x >> 4;
  const bf16* Bt = (sel == 0) ? Wq : (sel == 1) ? Wk : Wv;
  bf16* out = qkv + (size_t)sel * TEN;
  gemm_body<false>(X, Bt, out, blockIdx.y * 128, (blockIdx.x & 15) * 128, Cn, Cn);
}

__global__ __launch_bounds__(256) void out_gemm(const bf16* __restrict__ Y,
                                                const bf16* __restrict__ Wp,
                                                float* __restrict__ O) {
  gemm_body<true>(Y, Wp, O, blockIdx.y * 128, blockIdx.x * 128, Cn, Cn);
}

// ---------------------------------------------------------------------------
// RoPE in place. grid.y==0: q tensor, fold in scale*log2e for the softmax
// (exp2-based online softmax downstream). grid.y==1: k tensor, no scale.
// ---------------------------------------------------------------------------
__global__ __launch_bounds__(256) void rope_qk(bf16* __restrict__ qk) {
  const bool isq = (blockIdx.y == 0);
  bf16* p = qk + (size_t)blockIdx.y * TEN;
  const int idx = blockIdx.x * 256 + threadIdx.x;
  const int row = idx >> 10;
  const int pp  = idx & 1023;
  const int i   = pp & 63;
  const int col0 = (pp >> 6) * 128 + 2 * i;
  const int t = row & (Tn - 1);
  const float ang = (float)t * __expf(-(float)i * 0.14391156831212787f); // ln(1e4)/64
  float s, c;
  sincosf(ang, &s, &c);
  const float m = isq ? (0.08838834764831845f * 1.4426950408889634f) : 1.0f;
  uint32_t* addr = (uint32_t*)(p + (size_t)row * Cn + col0);
  const uint32_t u = *addr;
  const float xe = __uint_as_float((u & 0xffffu) << 16);
  const float xo = __uint_as_float(u & 0xffff0000u);
  const bf16 re = (bf16)((xe * c - xo * s) * m);
  const bf16 ro = (bf16)((xo * c + xe * s) * m);
  *addr = ((uint32_t)__builtin_bit_cast(uint16_t, ro) << 16) |
          (uint32_t)__builtin_bit_cast(uint16_t, re);
}

// ---------------------------------------------------------------------------
// V transpose: v (B*T, C) -> vt (B, C, T), 64x64 tiles, LDS stride 65.
// ---------------------------------------------------------------------------
__global__ __launch_bounds__(256) void transpose_v(const bf16* __restrict__ v,
                                                   bf16* __restrict__ vt) {
  __shared__ bf16 tile[64 * 65];
  const int tid = threadIdx.x;
  const int t0 = blockIdx.x * 64, c0 = blockIdx.y * 64, b = blockIdx.z;
  const bf16* src = v + ((size_t)(b * Tn + t0)) * Cn + c0;
  bf16* dst = vt + ((size_t)(b * Cn + c0)) * Tn + t0;
#pragma unroll
  for (int i = 0; i < 16; i++) {
    int lin = i * 256 + tid;
    int r = lin >> 6, c = lin & 63;
    tile[r * 65 + c] = src[(size_t)r * Cn + c];
  }
  __syncthreads();
#pragma unroll
  for (int i = 0; i < 16; i++) {
    int lin = i * 256 + tid;
    int cc = lin >> 6, t = lin & 63;
    dst[(size_t)cc * Tn + t] = tile[t * 65 + cc];
  }
}

// ---------------------------------------------------------------------------
// Causal flash attention. Block = 128 q-rows of one (b,h); wave w owns rows
// [w*32, w*32+32) as two 16-row MFMA tiles. 64-key tiles, online softmax in
// exp2 domain (scale*log2e pre-folded into q). Heavy tiles dispatched first.
// ---------------------------------------------------------------------------
__global__ __launch_bounds__(256, 2) void attn(const bf16* __restrict__ q,
                                               const bf16* __restrict__ k,
                                               const bf16* __restrict__ vt,
                                               bf16* __restrict__ y) {
  __shared__ bf16 sK[64 * 136];    // K tile (64 keys x 128 d), stride 136
  __shared__ bf16 sVt[128 * 72];   // V^T tile (128 d x 64 keys), stride 72
  __shared__ bf16 sP[128 * 72];    // P tile (128 q x 64 keys), stride 72

  const int tid = threadIdx.x;
  const int bh = blockIdx.x;
  const int qt = 15 - blockIdx.y;          // heavy blocks first
  const int b = bh >> 4, h = bh & 15;
  const int q0 = qt * 128;
  const int lane = tid & 63, w = tid >> 6;
  const int quad = lane >> 4, l16 = lane & 15;

  const bf16* qbase  = q + ((size_t)(b * Tn + q0)) * Cn + h * HD;
  const bf16* kbase  = k + ((size_t)(b * Tn)) * Cn + h * HD;
  const bf16* vtbase = vt + ((size_t)(b * Cn + h * HD)) * Tn;

  // Q fragment preload straight from global (one-time, 16B/lane)
  bf16x8 qf[2][4];
#pragma unroll
  for (int im = 0; im < 2; im++)
#pragma unroll
    for (int s = 0; s < 4; s++)
      qf[im][s] = *(const bf16x8*)(qbase +
          (size_t)(w * 32 + im * 16 + l16) * Cn + s * 32 + quad * 8);

  f32x4 O[2][8] = {};
  float mrow[2][4], lrow[2][4];
#pragma unroll
  for (int im = 0; im < 2; im++)
#pragma unroll
    for (int r = 0; r < 4; r++) { mrow[im][r] = -1e30f; lrow[im][r] = 0.f; }

  const int nkt = 2 * qt + 2;
  for (int kt = 0; kt < nkt; kt++) {
#pragma unroll
    for (int i = 0; i < 4; i++) {            // stage K tile
      int lin = i * 256 + tid;
      int row = lin >> 4, c8 = (lin & 15) * 8;
      *(uint4*)&sK[row * 136 + c8] =
          *(const uint4*)(kbase + (size_t)(kt * 64 + row) * Cn + c8);
    }
#pragma unroll
    for (int i = 0; i < 4; i++) {            // stage V^T tile
      int lin = i * 256 + tid;
      int drow = lin >> 3, k8 = (lin & 7) * 8;
      *(uint4*)&sVt[drow * 72 + k8] =
          *(const uint4*)(vtbase + (size_t)drow * Tn + kt * 64 + k8);
    }
    __syncthreads();

    // wave-uniform skip: this wave's rows all < every key in the tile
    if (kt * 64 <= q0 + w * 32 + 31) {
      f32x4 sv[2][4] = {};
#pragma unroll
      for (int s = 0; s < 4; s++)
#pragma unroll
        for (int jn = 0; jn < 4; jn++) {
          bf16x8 kf = *(const bf16x8*)&sK[(jn * 16 + l16) * 136 + s * 32 + quad * 8];
          sv[0][jn] = MFMA16(qf[0][s], kf, sv[0][jn]);
          sv[1][jn] = MFMA16(qf[1][s], kf, sv[1][jn]);
        }

      const bool anymask = (kt >= 2 * qt);   // only diagonal-overlapping tiles
#pragma unroll
      for (int im = 0; im < 2; im++)
#pragma unroll
        for (int r = 0; r < 4; r++) {
          float pv[4];
          float mx = -1e30f;
#pragma unroll
          for (int jn = 0; jn < 4; jn++) {
            float x = sv[im][jn][r];
            if (anymask) {
              int key = kt * 64 + jn * 16 + l16;
              int qr  = q0 + w * 32 + im * 16 + quad * 4 + r;
              if (key > qr) x = -1e30f;
            }
            pv[jn] = x;
            mx = fmaxf(mx, x);
          }
          mx = fmaxf(mx, __shfl_xor(mx, 1));
          mx = fmaxf(mx, __shfl_xor(mx, 2));
          mx = fmaxf(mx, __shfl_xor(mx, 4));
          mx = fmaxf(mx, __shfl_xor(mx, 8));
          const float mn = fmaxf(mrow[im][r], mx);
          const float alpha = exp2f(mrow[im][r] - mn);
          mrow[im][r] = mn;
          float rs = 0.f;
#pragma unroll
          for (int jn = 0; jn < 4; jn++) {
            float e = exp2f(pv[jn] - mn);
            sP[(w * 32 + im * 16 + quad * 4 + r) * 72 + jn * 16 + l16] = (bf16)e;
            rs += e;
          }
          rs += __shfl_xor(rs, 1);
          rs += __shfl_xor(rs, 2);
          rs += __shfl_xor(rs, 4);
          rs += __shfl_xor(rs, 8);
          lrow[im][r] = lrow[im][r] * alpha + rs;
#pragma unroll
          for (int n = 0; n < 8; n++) O[im][n][r] *= alpha;
        }

#pragma unroll
      for (int s2 = 0; s2 < 2; s2++) {
        bf16x8 pf0 = *(const bf16x8*)&sP[(w * 32 + l16) * 72 + s2 * 32 + quad * 8];
        bf16x8 pf1 = *(const bf16x8*)&sP[(w * 32 + 16 + l16) * 72 + s2 * 32 + quad * 8];
#pragma unroll
        for (int n = 0; n < 8; n++) {
          bf16x8 vf = *(const bf16x8*)&sVt[(n * 16 + l16) * 72 + s2 * 32 + quad * 8];
          O[0][n] = MFMA16(pf0, vf, O[0][n]);
          O[1][n] = MFMA16(pf1, vf, O[1][n]);
        }
      }
    }
    __syncthreads();
  }

#pragma unroll
  for (int im = 0; im < 2; im++) {
    bf16* ybase = y + ((size_t)(b * Tn + q0 + w * 32 + im * 16)) * Cn + h * HD;
#pragma unroll
    for (int r = 0; r < 4; r++) {
      const float inv = 1.f / lrow[im][r];
#pragma unroll
      for (int n = 0; n < 8; n++)
        ybase[(size_t)(quad * 4 + r) * Cn + n * 16 + l16] = (bf16)(O[im][n][r] * inv);
    }
  }
}

// ---------------------------------------------------------------------------
extern "C" void kernel_launch(void* const* d_in, const int* in_sizes, int n_in,
                              void* d_out, int out_size, void* d_ws, size_t ws_size,
                              hipStream_t stream) {
  (void)in_sizes; (void)n_in; (void)out_size; (void)ws_size;
  const float* x  = (const float*)d_in[0];
  const float* Wq = (const float*)d_in[1];
  const float* Wk = (const float*)d_in[2];
  const float* Wv = (const float*)d_in[3];
  const float* Wp = (const float*)d_in[4];
  float* out = (float*)d_out;
  bf16*  ws  = (bf16*)d_ws;

  bf16* q   = ws;                    // (B*T, C)
  bf16* kk  = ws + TEN;              // (B*T, C)
  bf16* v   = ws + 2 * TEN;          // (B*T, C)
  bf16* vt  = ws + 3 * TEN;          // (B, C, T)
  bf16* wqb = ws + 3 * TEN;          // alias vt (dead after qkv_gemm)
  bf16* wkb = ws + 3 * TEN + TEN / 4;
  bf16* wvb = ws + 3 * TEN + TEN / 2;
  bf16* xb  = ws + 4 * TEN;          // alias y (dead after qkv_gemm)
  bf16* y   = ws + 4 * TEN;
  bf16* wpb = ws + 5 * TEN;

  to_bf16    <<<dim3(8192), 256, 0, stream>>>(x, xb);
  to_bf16    <<<dim3(2048), 256, 0, stream>>>(Wq, wqb);
  to_bf16    <<<dim3(2048), 256, 0, stream>>>(Wk, wkb);
  to_bf16    <<<dim3(2048), 256, 0, stream>>>(Wv, wvb);
  to_bf16    <<<dim3(2048), 256, 0, stream>>>(Wp, wpb);
  qkv_gemm   <<<dim3(48, 64), 256, 0, stream>>>(xb, wqb, wkb, wvb, ws);
  rope_qk    <<<dim3(32768, 2), 256, 0, stream>>>(ws);
  transpose_v<<<dim3(32, 32, 4), 256, 0, stream>>>(v, vt);
  attn       <<<dim3(64, 16), 256, 0, stream>>>(q, kk, vt, y);
  out_gemm   <<<dim3(16, 64), 256, 0, stream>>>(y, wpb, out);
}